// Round 10
// baseline (515.278 us; speedup 1.0000x reference)
//
#include <hip/hip_runtime.h>
#include <hip/hip_bf16.h>

// ---------------------------------------------------------------------------
// VoxelBackBone8x, R20: B-direct-from-global (no Bbuf) in all conv kernels.
// Volume model (validated R17/R18/R19): time ~ dma16-staged bytes @ ~6GB/ms,
// paid in per-batch vmcnt(0) drains. Weights (<=229KB, L2-hot, identical
// across blocks) were ~230MB of that volume. R20 reads B fragments directly
// from global into VGPRs (coalesced 1KB/wave, compiler-scheduled, not in the
// barrier drain); LDS-DMA kept for the scattered A gathers only (R12 proved
// A-direct fails). Dense now has ONE barrier (halo). Freed LDS: L8-L10 MB
// 1->2, L3/L4 MB 2->3, dense MB 2->3.
// Verified MFMA layouts (learn_hip m89/m91):
//   A[m=lane&15][k=quad*8+j], B[n=lane&15][k=quad*8+j],
//   C/D col=lane&15, row=quad*4+reg.
// ---------------------------------------------------------------------------

typedef __attribute__((ext_vector_type(8))) short bf16x8;
typedef __attribute__((ext_vector_type(4))) short bf16x4s;
typedef __attribute__((ext_vector_type(4))) float f32x4;

typedef const __attribute__((address_space(1))) unsigned int* gas_ptr;
typedef __attribute__((address_space(3))) unsigned int* las_ptr;

__device__ __forceinline__ void dma16(const unsigned short* g, unsigned short* l) {
    __builtin_amdgcn_global_load_lds((gas_ptr)g, (las_ptr)l, 16, 0, 0);
}

// bijective XCD swizzle (m204)
__device__ __forceinline__ int xcd_swz(int wg, int nwg) {
    const int x = wg & 7, i = wg >> 3;
    const int q = nwg >> 3, r = nwg & 7;
    return (x < r ? x * (q + 1) : r * (q + 1) + (x - r) * q) + i;
}

__device__ inline unsigned short f2bf(float f) {
    unsigned u = __builtin_bit_cast(unsigned, f);
    u += 0x7FFFu + ((u >> 16) & 1u);
    return (unsigned short)(u >> 16);
}

struct ScatterArgs {
    const int* coords[4];
    int* grid[4];
    int n[4];
    int D[4], H[4], W[4];
};

__global__ __launch_bounds__(256) void scatter_grid_all(ScatterArgs a) {
    const int l = blockIdx.y;
    const int i = blockIdx.x * 256 + threadIdx.x;
    if (i >= a.n[l]) return;
    const int* c = a.coords[l] + 4 * i;
    a.grid[l][((c[0] * a.D[l] + c[1]) * a.H[l] + c[2]) * a.W[l] + c[3]] = i;
}

struct PrepArgs {
    const float* src[11];
    unsigned short* dst[11];
    int T[11], CIN[11], COUT[11], total[11];
};

// fp32 [t][cin][cout] -> bf16 [t][cout][cin]; pad tap T zeroed
__global__ __launch_bounds__(256) void prep_w_all(PrepArgs a) {
    const int l = blockIdx.y;
    const int i = blockIdx.x * 256 + threadIdx.x;
    if (i >= a.total[l]) return;
    const int COUT = a.COUT[l], CIN = a.CIN[l], T = a.T[l];
    const int co = i % COUT; const int r = i / COUT; const int ci = r % CIN; const int t = r / CIN;
    unsigned short v = (t < T) ? f2bf(a.src[l][i]) : (unsigned short)0;
    a.dst[l][((size_t)t * COUT + co) * CIN + ci] = v;
}

// Layer 0: CIN=4 -> COUT=16
__global__ __launch_bounds__(256, 4) void sp_conv0(const float* __restrict__ fin,
                                                   const int* __restrict__ grid,
                                                   const int* __restrict__ oc, int n_out,
                                                   const float* __restrict__ w,
                                                   float* __restrict__ out,
                                                   int D, int H, int W) {
    const int c = threadIdx.x & 15;
    const int p = (blockIdx.x * 256 + threadIdx.x) >> 4;
    if (p >= n_out) return;
    const int b   = oc[4*p+0];
    const int iz0 = oc[4*p+1] - 1;
    const int iy0 = oc[4*p+2] - 1;
    const int ix0 = oc[4*p+3] - 1;
    const int* gb = grid + b * (D * H * W);
    float acc = 0.f;
    for (int kd = 0; kd < 3; ++kd) {
        const int iz = iz0 + kd;
        if ((unsigned)iz >= (unsigned)D) continue;
        for (int kh = 0; kh < 3; ++kh) {
            const int iy = iy0 + kh;
            if ((unsigned)iy >= (unsigned)H) continue;
            for (int kw = 0; kw < 3; ++kw) {
                const int ix = ix0 + kw;
                if ((unsigned)ix >= (unsigned)W) continue;
                const int idx = gb[(iz*H + iy)*W + ix];
                if (idx < 0) continue;
                const float4 v = *(const float4*)(fin + (size_t)idx * 4);
                const float* wp = w + (size_t)((kd*3 + kh)*3 + kw) * 64 + c;
                acc = fmaf(v.x, wp[0],  acc);
                acc = fmaf(v.y, wp[16], acc);
                acc = fmaf(v.z, wp[32], acc);
                acc = fmaf(v.w, wp[48], acc);
            }
        }
    }
    out[(size_t)p*16 + c] = acc;
}

// ---------------------------------------------------------------------------
// LDS path, CIN=16 (layers 1,2). A staged via dma16; B direct from global.
// ---------------------------------------------------------------------------
template<int COUT>
__global__ __launch_bounds__(256, 4) void sp_conv_lds16(
    const unsigned short* __restrict__ fin, const int* __restrict__ grid,
    const int* __restrict__ oc, int n_out,
    const unsigned short* __restrict__ wt, float* __restrict__ out,
    float* __restrict__ stats,
    int D, int H, int W, int sz, int sy, int sx, int pz, int py, int px)
{
    constexpr int T  = 27;
    constexpr int BT = 4;
    constexpr int TP = 28;
    constexpr int NT = COUT/16;

    __shared__ unsigned short Abuf[4*BT*16*16];
    __shared__ float ls[2*COUT];

    const int l     = threadIdx.x & 63;
    const int w     = threadIdx.x >> 6;
    const int n     = l & 15;
    const int quad  = l >> 4;
    const int pbase = xcd_swz(blockIdx.x, gridDim.x) * 64 + w * 16;

    if (threadIdx.x < 2*COUT) ls[threadIdx.x] = 0.f;

    int idx[TP];
    if (quad == 0) {
        int pc = pbase + n;
        if (pc > n_out - 1) pc = n_out - 1;
        const int4 cc = ((const int4*)oc)[pc];
        const int* gb = grid + cc.x * (D * H * W);
        const int iz0 = cc.y * sz - pz;
        const int iy0 = cc.z * sy - py;
        const int ix0 = cc.w * sx - px;
#pragma unroll
        for (int tap = 0; tap < TP; ++tap) {
            const int te = tap < T ? tap : 0;
            const int kd = te/9, kr = te%9, kh = kr/3, kw = kr%3;
            const int iz = iz0 + kd, iy = iy0 + kh, ix = ix0 + kw;
            const bool ok = (tap < T) && (unsigned)iz < (unsigned)D &&
                            (unsigned)iy < (unsigned)H && (unsigned)ix < (unsigned)W;
            const int cz = iz < 0 ? 0 : (iz >= D ? D-1 : iz);
            const int cy = iy < 0 ? 0 : (iy >= H ? H-1 : iy);
            const int cx = ix < 0 ? 0 : (ix >= W ? W-1 : ix);
            const int g = gb[(cz*H + cy)*W + cx];
            idx[tap] = ok ? g : -1;
        }
    }

    f32x4 acc[NT];
#pragma unroll
    for (int t = 0; t < NT; ++t) acc[t] = (f32x4){0.f, 0.f, 0.f, 0.f};

    const int h  = l >> 5;
    const int m  = (l >> 1) & 15;
    const int ch = l & 1;

#pragma unroll
    for (int tb0 = 0; tb0 < TP; tb0 += BT) {
#pragma unroll
        for (int q = 0; q < BT/2; ++q) {
            const int v0 = __shfl(idx[tb0 + 2*q],     m);
            const int v1 = __shfl(idx[tb0 + 2*q + 1], m);
            const int row = h ? v1 : v0;
            const unsigned short* gp = fin + (ptrdiff_t)row*16 + ch*8;
            unsigned short* lp = Abuf + (w*BT + 2*q)*16*16;
            dma16(gp, lp);
        }
        __syncthreads();
#pragma unroll
        for (int jp = 0; jp < BT/2; ++jp) {
            const int ts  = 2*jp + (quad >> 1);
            const int tap = tb0 + ts;              // wt[27] is the zeroed pad tap
            bf16x8 a = *(const bf16x8*)(Abuf + ((w*BT + ts)*16 + n)*16 + (quad & 1)*8);
#pragma unroll
            for (int t = 0; t < NT; ++t) {
                bf16x8 b = *(const bf16x8*)(wt + ((size_t)tap*COUT + t*16 + n)*16 + (quad & 1)*8);
                acc[t] = __builtin_amdgcn_mfma_f32_16x16x32_bf16(a, b, acc[t], 0, 0, 0);
            }
        }
        __syncthreads();
    }

#pragma unroll
    for (int t = 0; t < NT; ++t)
#pragma unroll
        for (int r = 0; r < 4; ++r) {
            const int p = pbase + quad*4 + r;
            if (p < n_out) out[(size_t)p * COUT + t*16 + n] = acc[t][r];
        }

#pragma unroll
    for (int t = 0; t < NT; ++t) {
        float s1 = 0.f, s2 = 0.f;
#pragma unroll
        for (int r = 0; r < 4; ++r) {
            const int p = pbase + quad*4 + r;
            if (p < n_out) { const float v = acc[t][r]; s1 += v; s2 += v*v; }
        }
        s1 += __shfl_xor(s1, 16); s2 += __shfl_xor(s2, 16);
        s1 += __shfl_xor(s1, 32); s2 += __shfl_xor(s2, 32);
        if (quad == 0) {
            atomicAdd(&ls[t*16 + n], s1);
            atomicAdd(&ls[COUT + t*16 + n], s2);
        }
    }
    __syncthreads();
    if (threadIdx.x < 2*COUT) atomicAdd(&stats[threadIdx.x], ls[threadIdx.x]);
}

// ---------------------------------------------------------------------------
// 64-pt LDS path, CIN>=32: small-N layers (L8-L11). B direct from global.
// ---------------------------------------------------------------------------
template<int CIN, int COUT, int BT, int KD, int KH, int KW, int MB>
__global__ __launch_bounds__(256, MB) void sp_conv_lds(
    const unsigned short* __restrict__ fin, const int* __restrict__ grid,
    const int* __restrict__ oc, int n_out,
    const unsigned short* __restrict__ wt, float* __restrict__ out,
    float* __restrict__ stats,
    int D, int H, int W, int sz, int sy, int sx, int pz, int py, int px)
{
    constexpr int T    = KD*KH*KW;
    constexpr int TP   = ((T + BT - 1)/BT)*BT;
    constexpr int NT   = COUT/16;
    constexpr int S    = CIN/32;
    constexpr int LPR  = CIN/8;
    constexpr int RPD  = 64/LPR;
    constexpr int ADMA = 16/RPD;

    __shared__ unsigned short Abuf[4*BT*16*CIN];
    __shared__ float ls[2*COUT];

    const int l     = threadIdx.x & 63;
    const int w     = threadIdx.x >> 6;
    const int n     = l & 15;
    const int quad  = l >> 4;
    const int pbase = xcd_swz(blockIdx.x, gridDim.x) * 64 + w * 16;

    if (threadIdx.x < 2*COUT) ls[threadIdx.x] = 0.f;

    int idx[TP];
    if (quad == 0) {
        int pc = pbase + n;
        if (pc > n_out - 1) pc = n_out - 1;
        const int4 cc = ((const int4*)oc)[pc];
        const int* gb = grid + cc.x * (D * H * W);
        const int iz0 = cc.y * sz - pz;
        const int iy0 = cc.z * sy - py;
        const int ix0 = cc.w * sx - px;
#pragma unroll
        for (int tap = 0; tap < TP; ++tap) {
            const int te = tap < T ? tap : 0;
            const int kd = te/(KH*KW), kr = te%(KH*KW), kh = kr/KW, kw = kr%KW;
            const int iz = iz0 + kd, iy = iy0 + kh, ix = ix0 + kw;
            const bool ok = (tap < T) && (unsigned)iz < (unsigned)D &&
                            (unsigned)iy < (unsigned)H && (unsigned)ix < (unsigned)W;
            const int cz = iz < 0 ? 0 : (iz >= D ? D-1 : iz);
            const int cy = iy < 0 ? 0 : (iy >= H ? H-1 : iy);
            const int cx = ix < 0 ? 0 : (ix >= W ? W-1 : ix);
            const int g = gb[(cz*H + cy)*W + cx];
            idx[tap] = ok ? g : -1;
        }
    }

    f32x4 acc[NT];
#pragma unroll
    for (int t = 0; t < NT; ++t) acc[t] = (f32x4){0.f, 0.f, 0.f, 0.f};

#pragma unroll
    for (int tb0 = 0; tb0 < TP; tb0 += BT) {
#pragma unroll
        for (int j = 0; j < BT; ++j) {
#pragma unroll
            for (int d = 0; d < ADMA; ++d) {
                const int m  = d*RPD + l/LPR;
                const int i0 = __shfl(idx[tb0+j], m);
                const int slot = (l % LPR) ^ (m % LPR);
                const unsigned short* gp = fin + (ptrdiff_t)i0*CIN + slot*8;
                unsigned short* lp = Abuf + ((w*BT + j)*16 + d*RPD)*CIN;
                dma16(gp, lp);
            }
        }
        __syncthreads();
#pragma unroll
        for (int j = 0; j < BT; ++j) {
            const int tap = tb0 + j;
            const int tw  = tap < T ? tap : T;     // wt[T] zeroed pad
            const unsigned short* Aw = Abuf + (w*BT + j)*16*CIN;
#pragma unroll
            for (int s = 0; s < S; ++s) {
                const int c = s*4 + quad;
                bf16x8 a = *(const bf16x8*)(Aw + n*CIN + ((c ^ (n % LPR)) * 8));
#pragma unroll
                for (int t = 0; t < NT; ++t) {
                    const int r = t*16 + n;
                    bf16x8 b = *(const bf16x8*)(wt + ((size_t)tw*COUT + r)*CIN + c*8);
                    acc[t] = __builtin_amdgcn_mfma_f32_16x16x32_bf16(a, b, acc[t], 0, 0, 0);
                }
            }
        }
        __syncthreads();
    }

#pragma unroll
    for (int t = 0; t < NT; ++t)
#pragma unroll
        for (int r = 0; r < 4; ++r) {
            const int p = pbase + quad*4 + r;
            if (p < n_out) out[(size_t)p * COUT + t*16 + n] = acc[t][r];
        }

#pragma unroll
    for (int t = 0; t < NT; ++t) {
        float s1 = 0.f, s2 = 0.f;
#pragma unroll
        for (int r = 0; r < 4; ++r) {
            const int p = pbase + quad*4 + r;
            if (p < n_out) { const float v = acc[t][r]; s1 += v; s2 += v*v; }
        }
        s1 += __shfl_xor(s1, 16); s2 += __shfl_xor(s2, 16);
        s1 += __shfl_xor(s1, 32); s2 += __shfl_xor(s2, 32);
        if (quad == 0) {
            atomicAdd(&ls[t*16 + n], s1);
            atomicAdd(&ls[COUT + t*16 + n], s2);
        }
    }
    __syncthreads();
    if (threadIdx.x < 2*COUT) atomicAdd(&stats[threadIdx.x], ls[threadIdx.x]);
}

// ---------------------------------------------------------------------------
// Multi-m-tile LDS path, CIN>=32, T=27: big layers (L3,L4,L5).
// B direct from global; A staged via dma16.
// ---------------------------------------------------------------------------
template<int CIN, int COUT, int BT, int MT, int MB>
__global__ __launch_bounds__(256, MB) void sp_conv_big(
    const unsigned short* __restrict__ fin, const int* __restrict__ grid,
    const int* __restrict__ oc, int n_out,
    const unsigned short* __restrict__ wt, float* __restrict__ out,
    float* __restrict__ stats,
    int D, int H, int W, int sz, int sy, int sx, int pz, int py, int px)
{
    constexpr int T    = 27;
    constexpr int TP   = ((T + BT - 1)/BT)*BT;
    constexpr int PPW  = MT*16;
    constexpr int NT   = COUT/16;
    constexpr int S    = CIN/32;
    constexpr int LPR  = CIN/8;
    constexpr int RPD  = 64/LPR;
    constexpr int ADMA = PPW/RPD;

    __shared__ unsigned short Abuf[4*BT*PPW*CIN];
    __shared__ float ls[2*COUT];

    const int l     = threadIdx.x & 63;
    const int w     = threadIdx.x >> 6;
    const int n     = l & 15;
    const int quad  = l >> 4;
    const int wbase = xcd_swz(blockIdx.x, gridDim.x) * (4*PPW) + w * PPW;

    if (threadIdx.x < 2*COUT) ls[threadIdx.x] = 0.f;

    int idx[TP];
    {
        int pc = wbase + (l % PPW);
        if (pc > n_out - 1) pc = n_out - 1;
        const int4 cc = ((const int4*)oc)[pc];
        const int* gb = grid + cc.x * (D * H * W);
        const int iz0 = cc.y * sz - pz;
        const int iy0 = cc.z * sy - py;
        const int ix0 = cc.w * sx - px;
#pragma unroll
        for (int tap = 0; tap < TP; ++tap) {
            const int te = tap < T ? tap : 0;
            const int kd = te/9, kr = te%9, kh = kr/3, kw = kr%3;
            const int iz = iz0 + kd, iy = iy0 + kh, ix = ix0 + kw;
            const bool ok = (tap < T) && (unsigned)iz < (unsigned)D &&
                            (unsigned)iy < (unsigned)H && (unsigned)ix < (unsigned)W;
            const int cz = iz < 0 ? 0 : (iz >= D ? D-1 : iz);
            const int cy = iy < 0 ? 0 : (iy >= H ? H-1 : iy);
            const int cx = ix < 0 ? 0 : (ix >= W ? W-1 : ix);
            const int g = gb[(cz*H + cy)*W + cx];
            idx[tap] = ok ? g : -1;
        }
    }

    f32x4 acc[MT][NT];
#pragma unroll
    for (int mt = 0; mt < MT; ++mt)
#pragma unroll
        for (int t = 0; t < NT; ++t) acc[mt][t] = (f32x4){0.f, 0.f, 0.f, 0.f};

#pragma unroll
    for (int tb0 = 0; tb0 < TP; tb0 += BT) {
#pragma unroll
        for (int j = 0; j < BT; ++j) {
#pragma unroll
            for (int d = 0; d < ADMA; ++d) {
                const int r  = d*RPD + l/LPR;
                const int i0 = __shfl(idx[tb0+j], r);
                const int slot = (l % LPR) ^ (r % LPR);
                const unsigned short* gp = fin + (ptrdiff_t)i0*CIN + slot*8;
                unsigned short* lp = Abuf + ((w*BT + j)*PPW + d*RPD)*CIN;
                dma16(gp, lp);
            }
        }
        __syncthreads();
#pragma unroll
        for (int j = 0; j < BT; ++j) {
            const int tap = tb0 + j;
            const int tw  = tap < T ? tap : T;     // wt[T] zeroed pad
            const unsigned short* Aw = Abuf + (w*BT + j)*PPW*CIN;
#pragma unroll
            for (int s = 0; s < S; ++s) {
                const int c = s*4 + quad;
                bf16x8 bfr[NT];
#pragma unroll
                for (int t = 0; t < NT; ++t) {
                    const int r = t*16 + n;
                    bfr[t] = *(const bf16x8*)(wt + ((size_t)tw*COUT + r)*CIN + c*8);
                }
#pragma unroll
                for (int mt = 0; mt < MT; ++mt) {
                    bf16x8 a = *(const bf16x8*)(Aw + (mt*16 + n)*CIN + ((c ^ (n % LPR)) * 8));
#pragma unroll
                    for (int t = 0; t < NT; ++t)
                        acc[mt][t] = __builtin_amdgcn_mfma_f32_16x16x32_bf16(a, bfr[t], acc[mt][t], 0, 0, 0);
                }
            }
        }
        __syncthreads();
    }

#pragma unroll
    for (int mt = 0; mt < MT; ++mt)
#pragma unroll
        for (int t = 0; t < NT; ++t)
#pragma unroll
            for (int r = 0; r < 4; ++r) {
                const int p = wbase + mt*16 + quad*4 + r;
                if (p < n_out) out[(size_t)p * COUT + t*16 + n] = acc[mt][t][r];
            }

#pragma unroll
    for (int t = 0; t < NT; ++t) {
        float s1 = 0.f, s2 = 0.f;
#pragma unroll
        for (int mt = 0; mt < MT; ++mt)
#pragma unroll
            for (int r = 0; r < 4; ++r) {
                const int p = wbase + mt*16 + quad*4 + r;
                if (p < n_out) { const float v = acc[mt][t][r]; s1 += v; s2 += v*v; }
            }
        s1 += __shfl_xor(s1, 16); s2 += __shfl_xor(s2, 16);
        s1 += __shfl_xor(s1, 32); s2 += __shfl_xor(s2, 32);
        if (quad == 0) {
            atomicAdd(&ls[t*16 + n], s1);
            atomicAdd(&ls[COUT + t*16 + n], s2);
        }
    }
    __syncthreads();
    if (threadIdx.x < 2*COUT) atomicAdd(&stats[threadIdx.x], ls[threadIdx.x]);
}

// ---------------------------------------------------------------------------
// Dense tiled conv (stride 1, 3x3x3, pad 1, CIN==COUT==C=64): layers 6,7.
// Halo staged ONCE (one barrier); B direct from global.
// ---------------------------------------------------------------------------
template<int C, int TZ, int TY, int TX, int MB>
__global__ __launch_bounds__(256, MB) void sp_conv_dense(
    const unsigned short* __restrict__ dense, const int* __restrict__ grid,
    const unsigned short* __restrict__ wt, float* __restrict__ out,
    float* __restrict__ stats, const unsigned short* __restrict__ zrow,
    int D, int H, int W, int ZTn, int YTn, int XTn)
{
    constexpr int T   = 27;
    constexpr int HZ = TZ+2, HY = TY+2, HX = TX+2;
    constexpr int R   = HZ*HY*HX;
    constexpr int LPR = C/8;
    constexpr int RPD = 64/LPR;
    constexpr int RPI = 4*RPD;
    constexpr int NDMA = (R + RPI - 1)/RPI;
    constexpr int RPAD = NDMA*RPI;
    constexpr int M   = TZ*TY*TX;
    constexpr int WPW = M/4;
    constexpr int MT  = WPW/16;
    constexpr int NT  = C/16;
    constexpr int S   = C/32;

    __shared__ unsigned short Hbuf[RPAD*C];
    __shared__ float ls[2*C];

    const int l    = threadIdx.x & 63;
    const int w    = threadIdx.x >> 6;
    const int n    = l & 15;
    const int quad = l >> 4;

    int r1 = blockIdx.x;
    const int xt = r1 % XTn; r1 /= XTn;
    const int yt = r1 % YTn; r1 /= YTn;
    const int zt = r1 % ZTn; r1 /= ZTn;
    const int b  = r1;
    const int z0 = zt*TZ, y0 = yt*TY, x0 = xt*TX;
    const int* gb = grid + b * (D*H*W);
    const size_t dbase = (size_t)b * D*H*W;

    if (threadIdx.x < 2*C) ls[threadIdx.x] = 0.f;

#pragma unroll
    for (int d = 0; d < NDMA; ++d) {
        const int r0  = (d*4 + w)*RPD;
        const int row = r0 + l/LPR;
        const int slot = (l % LPR) ^ (row % LPR);
        const unsigned short* gp;
        if (row < R) {
            const int hz = row/(HY*HX);
            const int hy = (row/HX) % HY;
            const int hx = row % HX;
            const int gz = z0 - 1 + hz, gy = y0 - 1 + hy, gx = x0 - 1 + hx;
            const bool ok = (unsigned)gz < (unsigned)D && (unsigned)gy < (unsigned)H &&
                            (unsigned)gx < (unsigned)W;
            gp = ok ? dense + (dbase + (size_t)(gz*H + gy)*W + gx)*C + slot*8
                    : zrow + (l % LPR)*8;
        } else {
            gp = zrow + (l % LPR)*8;
        }
        dma16(gp, Hbuf + r0*C);
    }

    int prow[MT];
#pragma unroll
    for (int mt = 0; mt < MT; ++mt) {
        const int pos = w*WPW + mt*16 + n;
        const int dz = pos/(TY*TX), dy = (pos/TX)%TY, dx = pos%TX;
        prow[mt] = dz*(HY*HX) + dy*HX + dx;
    }

    f32x4 acc[MT][NT];
#pragma unroll
    for (int mt = 0; mt < MT; ++mt)
#pragma unroll
        for (int t = 0; t < NT; ++t) acc[mt][t] = (f32x4){0.f, 0.f, 0.f, 0.f};

    __syncthreads();                       // halo DMAs drained; ls init visible

#pragma unroll
    for (int tap = 0; tap < T; ++tap) {
        const int kd = tap/9, kh = (tap/3)%3, kw = tap%3;
        const int toff = kd*(HY*HX) + kh*HX + kw;
#pragma unroll
        for (int s = 0; s < S; ++s) {
            const int c = s*4 + quad;
            bf16x8 bfr[NT];
#pragma unroll
            for (int t = 0; t < NT; ++t) {
                const int rr = t*16 + n;
                bfr[t] = *(const bf16x8*)(wt + ((size_t)tap*C + rr)*C + c*8);
            }
#pragma unroll
            for (int mt = 0; mt < MT; ++mt) {
                const int arow = prow[mt] + toff;
                bf16x8 a = *(const bf16x8*)(Hbuf + arow*C + ((c ^ (arow & (LPR-1)))*8));
#pragma unroll
                for (int t = 0; t < NT; ++t)
                    acc[mt][t] = __builtin_amdgcn_mfma_f32_16x16x32_bf16(a, bfr[t], acc[mt][t], 0, 0, 0);
            }
        }
    }

    float s1[NT], s2[NT];
#pragma unroll
    for (int t = 0; t < NT; ++t) { s1[t] = 0.f; s2[t] = 0.f; }
#pragma unroll
    for (int mt = 0; mt < MT; ++mt) {
#pragma unroll
        for (int r = 0; r < 4; ++r) {
            const int pos = w*WPW + mt*16 + quad*4 + r;
            const int dz = pos/(TY*TX), dy = (pos/TX)%TY, dx = pos%TX;
            const int gz = z0 + dz, gy = y0 + dy, gx = x0 + dx;
            int p = -1;
            if (gz < D && gy < H && gx < W) p = gb[(gz*H + gy)*W + gx];
            if (p >= 0) {
#pragma unroll
                for (int t = 0; t < NT; ++t) {
                    const float v = acc[mt][t][r];
                    out[(size_t)p*C + t*16 + n] = v;
                    s1[t] += v; s2[t] += v*v;
                }
            }
        }
    }
#pragma unroll
    for (int t = 0; t < NT; ++t) {
        float a1 = s1[t], a2 = s2[t];
        a1 += __shfl_xor(a1, 16); a2 += __shfl_xor(a2, 16);
        a1 += __shfl_xor(a1, 32); a2 += __shfl_xor(a2, 32);
        if (quad == 0) {
            atomicAdd(&ls[t*16 + n], a1);
            atomicAdd(&ls[C + t*16 + n], a2);
        }
    }
    __syncthreads();
    if (threadIdx.x < 2*C) atomicAdd(&stats[threadIdx.x], ls[threadIdx.x]);
}

template<int C>
__global__ __launch_bounds__(256) void reduce_stats(const float* __restrict__ x, int nn,
                                                    float* __restrict__ stats)
{
    constexpr int R = 256 / C;
    __shared__ float s1[256];
    __shared__ float s2[256];
    const int c = threadIdx.x % C;
    const int r = threadIdx.x / C;
    float a1 = 0.f, a2 = 0.f;
    for (int i = blockIdx.x * R + r; i < nn; i += R * gridDim.x) {
        float v = x[(size_t)i*C + c];
        a1 += v;
        a2 += v * v;
    }
    s1[threadIdx.x] = a1;
    s2[threadIdx.x] = a2;
    __syncthreads();
    for (int off = 128; off >= C; off >>= 1) {
        if (threadIdx.x < off) {
            s1[threadIdx.x] += s1[threadIdx.x + off];
            s2[threadIdx.x] += s2[threadIdx.x + off];
        }
        __syncthreads();
    }
    if (threadIdx.x < C) {
        atomicAdd(&stats[c],     s1[threadIdx.x]);
        atomicAdd(&stats[C + c], s2[threadIdx.x]);
    }
}

__device__ inline void stv4(float* p, float4 v) { *(float4*)p = v; }
__device__ inline void stv4(unsigned short* p, float4 v) {
    bf16x4s o;
    o.x = (short)f2bf(v.x); o.y = (short)f2bf(v.y);
    o.z = (short)f2bf(v.z); o.w = (short)f2bf(v.w);
    *(bf16x4s*)p = o;
}

__device__ inline float4 bn_math(float4 xv, float4 s1, float4 s2, float4 gm, float4 bt,
                                 float inv_n) {
    float4 o;
    { float mu=s1.x*inv_n, var=s2.x*inv_n-mu*mu, g=gm.x*rsqrtf(var+1e-3f);
      float v=(xv.x-mu)*g+bt.x; o.x = v>0.f? v:0.f; }
    { float mu=s1.y*inv_n, var=s2.y*inv_n-mu*mu, g=gm.y*rsqrtf(var+1e-3f);
      float v=(xv.y-mu)*g+bt.y; o.y = v>0.f? v:0.f; }
    { float mu=s1.z*inv_n, var=s2.z*inv_n-mu*mu, g=gm.z*rsqrtf(var+1e-3f);
      float v=(xv.z-mu)*g+bt.z; o.z = v>0.f? v:0.f; }
    { float mu=s1.w*inv_n, var=s2.w*inv_n-mu*mu, g=gm.w*rsqrtf(var+1e-3f);
      float v=(xv.w-mu)*g+bt.w; o.w = v>0.f? v:0.f; }
    return o;
}

template<int C, typename OUT>
__global__ __launch_bounds__(256) void bn_relu_apply(const float* __restrict__ x,
                                                     OUT* __restrict__ y, int nn,
                                                     const float* __restrict__ stats,
                                                     const float* __restrict__ gamma,
                                                     const float* __restrict__ beta)
{
    const size_t q = (size_t)blockIdx.x * blockDim.x + threadIdx.x;
    if (q >= (size_t)nn * (C/4)) return;
    const int c = (int)(q % (size_t)(C/4)) * 4;
    const float4 o = bn_math(*(const float4*)(x + q*4),
                             *(const float4*)(stats + c), *(const float4*)(stats + C + c),
                             *(const float4*)(gamma + c), *(const float4*)(beta + c),
                             1.f / (float)nn);
    stv4(y + q*4, o);
}

// bn+relu writing into the dense [b,z,y,x,C] bf16 buffer (for dense conv input)
template<int C>
__global__ __launch_bounds__(256) void bn_relu_apply_dense(const float* __restrict__ x,
                                                           unsigned short* __restrict__ dense,
                                                           int nn,
                                                           const float* __restrict__ stats,
                                                           const float* __restrict__ gamma,
                                                           const float* __restrict__ beta,
                                                           const int* __restrict__ coords,
                                                           int D, int H, int W)
{
    const size_t q = (size_t)blockIdx.x * blockDim.x + threadIdx.x;
    if (q >= (size_t)nn * (C/4)) return;
    const int c = (int)(q % (size_t)(C/4)) * 4;
    const int p = (int)(q / (size_t)(C/4));
    const float4 o = bn_math(*(const float4*)(x + q*4),
                             *(const float4*)(stats + c), *(const float4*)(stats + C + c),
                             *(const float4*)(gamma + c), *(const float4*)(beta + c),
                             1.f / (float)nn);
    const int4 cc = ((const int4*)coords)[p];
    const size_t cell = ((size_t)((cc.x*D + cc.y)*H + cc.z)*W + cc.w);
    stv4(dense + cell*C + c, o);
}

extern "C" void kernel_launch(void* const* d_in, const int* in_sizes, int n_in,
                              void* d_out, int out_size, void* d_ws, size_t ws_size,
                              hipStream_t stream) {
    const float* WPTR[12] = {
        (const float*)d_in[1], (const float*)d_in[2], (const float*)d_in[3],
        (const float*)d_in[4], (const float*)d_in[5], (const float*)d_in[6],
        (const float*)d_in[7], (const float*)d_in[8], (const float*)d_in[9],
        (const float*)d_in[10], (const float*)d_in[11], (const float*)d_in[12] };
    const float* vf    = (const float*)d_in[0];
    const float* gamma = (const float*)d_in[13];
    const float* beta  = (const float*)d_in[14];
    const int* c1 = (const int*)d_in[15];
    const int* c2 = (const int*)d_in[16];
    const int* c3 = (const int*)d_in[17];
    const int* c4 = (const int*)d_in[18];
    const int* c5 = (const int*)d_in[19];
    const int N1 = in_sizes[15] / 4;
    const int N2 = in_sizes[16] / 4;
    const int N3 = in_sizes[17] / 4;
    const int N4 = in_sizes[18] / 4;
    const int N5 = in_sizes[19] / 4;

    static const int LT[12]  = {27,27,27,27,27,27,27,27,27,27,27,3};
    static const int LCI[12] = {4,16,16,32,32,32,64,64,64,64,64,64};
    static const int LCO[12] = {16,16,32,32,32,64,64,64,64,64,64,128};

    const size_t G1 = (size_t)2*41*160*160;
    const size_t G2 = (size_t)2*21*80*80;
    const size_t G3 = (size_t)2*11*40*40;
    const size_t G4 = (size_t)2*5*20*20;
    int* grid1 = (int*)d_ws;
    int* grid2 = grid1 + G1;
    int* grid3 = grid2 + G2;
    int* grid4 = grid3 + G3;
    float* stats = (float*)(grid4 + G4);

    size_t maxE = (size_t)N1*16;
    if ((size_t)N2*32  > maxE) maxE = (size_t)N2*32;
    if ((size_t)N3*64  > maxE) maxE = (size_t)N3*64;
    if ((size_t)N4*64  > maxE) maxE = (size_t)N4*64;
    if ((size_t)N5*128 > maxE) maxE = (size_t)N5*128;
    maxE = (maxE + 7) & ~(size_t)7;

    float* raw = stats + 12*256;
    unsigned short* padA = (unsigned short*)(raw + maxE);
    unsigned short* fA   = padA + 128;              // zero row at fA - CIN
    unsigned short* padB = fA + maxE;
    unsigned short* fB   = padB + 128;
    unsigned short* wtb  = fB + maxE;
    size_t wtoff[12];
    size_t wtot = 0;
    {
        size_t o = 0;
        for (int i = 1; i < 12; ++i) {
            wtoff[i] = o;
            o += (size_t)(LT[i] + 1) * LCI[i] * LCO[i];
        }
        wtot = (o + 15) & ~(size_t)15;
    }
    unsigned short* dbuf = wtb + wtot;              // dense buffer: 2*11*40*40*64 shorts

    hipMemsetAsync(grid1, 0xFF, (G1+G2+G3+G4)*sizeof(int), stream);
    hipMemsetAsync(stats, 0, 12*256*sizeof(float), stream);
    hipMemsetAsync(padA, 0, 128*sizeof(unsigned short), stream);
    hipMemsetAsync(padB, 0, 128*sizeof(unsigned short), stream);

    {
        ScatterArgs sa;
        sa.coords[0]=c1; sa.coords[1]=c2; sa.coords[2]=c3; sa.coords[3]=c4;
        sa.grid[0]=grid1; sa.grid[1]=grid2; sa.grid[2]=grid3; sa.grid[3]=grid4;
        sa.n[0]=N1; sa.n[1]=N2; sa.n[2]=N3; sa.n[3]=N4;
        sa.D[0]=41; sa.H[0]=160; sa.W[0]=160;
        sa.D[1]=21; sa.H[1]= 80; sa.W[1]= 80;
        sa.D[2]=11; sa.H[2]= 40; sa.W[2]= 40;
        sa.D[3]= 5; sa.H[3]= 20; sa.W[3]= 20;
        int mx = N1; if (N2>mx) mx=N2; if (N3>mx) mx=N3; if (N4>mx) mx=N4;
        dim3 g((mx + 255)/256, 4);
        scatter_grid_all<<<g, 256, 0, stream>>>(sa);
    }
    {
        PrepArgs pa;
        int mx = 0;
        for (int i = 1; i < 12; ++i) {
            pa.src[i-1] = WPTR[i];
            pa.dst[i-1] = wtb + wtoff[i];
            pa.T[i-1] = LT[i]; pa.CIN[i-1] = LCI[i]; pa.COUT[i-1] = LCO[i];
            pa.total[i-1] = (LT[i]+1)*LCI[i]*LCO[i];
            if (pa.total[i-1] > mx) mx = pa.total[i-1];
        }
        dim3 g((mx + 255)/256, 11);
        prep_w_all<<<g, 256, 0, stream>>>(pa);
    }

    enum { GOFF_0 = 0, GOFF_1 = 16, GOFF_2 = 32, GOFF_3 = 64, GOFF_4 = 96, GOFF_5 = 128,
           GOFF_6 = 192, GOFF_7 = 256, GOFF_8 = 320, GOFF_9 = 384, GOFF_10 = 448, GOFF_11 = 512 };

#define APPLY(i, COUT, NP, FOUT_T, FOUT) \
    bn_relu_apply<COUT, FOUT_T><<<(((size_t)(NP)*(COUT)/4) + 255)/256, 256, 0, stream>>>( \
        raw, FOUT, NP, stats + (i)*256, gamma + GOFF_##i, beta + GOFF_##i);

#define APPLYD(i, C, NP, CC, D,H,W) \
    hipMemsetAsync(dbuf, 0, (size_t)2*(D)*(H)*(W)*(C)*2, stream); \
    bn_relu_apply_dense<C><<<(((size_t)(NP)*(C)/4) + 255)/256, 256, 0, stream>>>( \
        raw, dbuf, NP, stats + (i)*256, gamma + GOFF_##i, beta + GOFF_##i, CC, D,H,W);

    sp_conv0<<<((size_t)N1*16 + 255)/256, 256, 0, stream>>>(vf, grid1, c1, N1, WPTR[0], raw, 41,160,160);
    { int rb = (N1 + 15)/16; if (rb > 240) rb = 240;
      reduce_stats<16><<<rb, 256, 0, stream>>>(raw, N1, stats + 0*256); }
    APPLY(0, 16, N1, unsigned short, fA);

#define CONVS(i, COUT, FIN, GRD, OC, NP, D,H,W, SZ,SY,SX, PZ,PY,PX) \
    sp_conv_lds16<COUT><<<((NP)+63)/64, 256, 0, stream>>>( \
        FIN, GRD, OC, NP, wtb + wtoff[i], raw, stats + (i)*256, D,H,W, SZ,SY,SX, PZ,PY,PX);

#define CONVL(i, CIN, COUT, BT, MB, KD,KH,KW, FIN, GRD, OC, NP, D,H,W, SZ,SY,SX, PZ,PY,PX) \
    sp_conv_lds<CIN,COUT,BT,KD,KH,KW,MB><<<((NP)+63)/64, 256, 0, stream>>>( \
        FIN, GRD, OC, NP, wtb + wtoff[i], raw, stats + (i)*256, D,H,W, SZ,SY,SX, PZ,PY,PX);

#define CONVB(i, CIN, COUT, BT, MT, MB, FIN, GRD, OC, NP, D,H,W, SZ,SY,SX, PZ,PY,PX) \
    sp_conv_big<CIN,COUT,BT,MT,MB><<<((NP)+(64*(MT))-1)/(64*(MT)), 256, 0, stream>>>( \
        FIN, GRD, OC, NP, wtb + wtoff[i], raw, stats + (i)*256, D,H,W, SZ,SY,SX, PZ,PY,PX);

#define CONVD(i, C, TZ,TY,TX, MB, GRD, D,H,W) \
    { const int zt = ((D)+(TZ)-1)/(TZ), yt = ((H)+(TY)-1)/(TY), xt = ((W)+(TX)-1)/(TX); \
      sp_conv_dense<C,TZ,TY,TX,MB><<<2*zt*yt*xt, 256, 0, stream>>>( \
          dbuf, GRD, wtb + wtoff[i], raw, stats + (i)*256, padA, D,H,W, zt,yt,xt); }

    CONVS( 1, 16,       fA, grid1, c1, N1, 41,160,160, 1,1,1, 1,1,1); APPLY( 1, 16, N1, unsigned short, fB);
    CONVS( 2, 32,       fB, grid1, c2, N2, 41,160,160, 2,2,2, 1,1,1); APPLY( 2, 32, N2, unsigned short, fA);
    CONVB ( 3, 32, 32, 3, 4, 3, fA, grid2, c2, N2, 21, 80, 80, 1,1,1, 1,1,1); APPLY( 3, 32, N2, unsigned short, fB);
    CONVB ( 4, 32, 32, 3, 4, 3, fB, grid2, c2, N2, 21, 80, 80, 1,1,1, 1,1,1); APPLY( 4, 32, N2, unsigned short, fA);
    CONVB ( 5, 32, 64, 3, 2, 3, fA, grid2, c3, N3, 21, 80, 80, 2,2,2, 1,1,1); APPLYD( 5, 64, N3, c3, 11,40,40);
    CONVD ( 6, 64, 4,4,8, 3, grid3, 11,40,40);                          APPLYD( 6, 64, N3, c3, 11,40,40);
    CONVD ( 7, 64, 4,4,8, 3, grid3, 11,40,40);                          APPLY( 7, 64, N3, unsigned short, fB);
    CONVL ( 8, 64, 64, 9, 2, 3,3,3, fB, grid3, c4, N4, 11, 40, 40, 2,2,2, 0,1,1); APPLY( 8, 64, N4, unsigned short, fA);
    CONVL ( 9, 64, 64, 9, 2, 3,3,3, fA, grid4, c4, N4,  5, 20, 20, 1,1,1, 1,1,1); APPLY( 9, 64, N4, unsigned short, fB);
    CONVL (10, 64, 64, 9, 2, 3,3,3, fB, grid4, c4, N4,  5, 20, 20, 1,1,1, 1,1,1); APPLY(10, 64, N4, unsigned short, fA);
    CONVL (11, 64,128, 3, 2, 3,1,1, fA, grid4, c5, N5,  5, 20, 20, 2,1,1, 0,0,0); APPLY(11, 128, N5, float, (float*)d_out);
#undef CONVS
#undef CONVL
#undef CONVB
#undef CONVD
#undef APPLY
#undef APPLYD
}

// Round 11
// 382.386 us; speedup vs baseline: 1.3475x; 1.3475x over previous
//
#include <hip/hip_runtime.h>
#include <hip/hip_bf16.h>

// ---------------------------------------------------------------------------
// VoxelBackBone8x, R21 = R19 (validated best, 382.9us). R20 post-mortem:
// B-direct-from-global regressed 383->515us (dense 13->57.6us) -- per-lane
// B loads create load->MFMA dependency stalls (R12 failure mode; MfmaUtil
// AND VALUBusy both dropped). Model refined: staged-volume economics apply
// WITHIN the dma16 pipe; B belongs there (batched issue, one drain/batch).
// Config: R17 B-amortized multi-m-tile blocks (L3/L4 MT=4, L5 MT=2),
// R18 dense-halo L6/L7 (C=64, conflict-free), R19 pad-tap elimination.
// Verified MFMA layouts (learn_hip m89/m91):
//   A[m=lane&15][k=quad*8+j], B[n=lane&15][k=quad*8+j],
//   C/D col=lane&15, row=quad*4+reg.
// ---------------------------------------------------------------------------

typedef __attribute__((ext_vector_type(8))) short bf16x8;
typedef __attribute__((ext_vector_type(4))) short bf16x4s;
typedef __attribute__((ext_vector_type(4))) float f32x4;

typedef const __attribute__((address_space(1))) unsigned int* gas_ptr;
typedef __attribute__((address_space(3))) unsigned int* las_ptr;

__device__ __forceinline__ void dma16(const unsigned short* g, unsigned short* l) {
    __builtin_amdgcn_global_load_lds((gas_ptr)g, (las_ptr)l, 16, 0, 0);
}

// bijective XCD swizzle (m204)
__device__ __forceinline__ int xcd_swz(int wg, int nwg) {
    const int x = wg & 7, i = wg >> 3;
    const int q = nwg >> 3, r = nwg & 7;
    return (x < r ? x * (q + 1) : r * (q + 1) + (x - r) * q) + i;
}

__device__ inline unsigned short f2bf(float f) {
    unsigned u = __builtin_bit_cast(unsigned, f);
    u += 0x7FFFu + ((u >> 16) & 1u);
    return (unsigned short)(u >> 16);
}

struct ScatterArgs {
    const int* coords[4];
    int* grid[4];
    int n[4];
    int D[4], H[4], W[4];
};

__global__ __launch_bounds__(256) void scatter_grid_all(ScatterArgs a) {
    const int l = blockIdx.y;
    const int i = blockIdx.x * 256 + threadIdx.x;
    if (i >= a.n[l]) return;
    const int* c = a.coords[l] + 4 * i;
    a.grid[l][((c[0] * a.D[l] + c[1]) * a.H[l] + c[2]) * a.W[l] + c[3]] = i;
}

struct PrepArgs {
    const float* src[11];
    unsigned short* dst[11];
    int T[11], CIN[11], COUT[11], total[11];
};

// fp32 [t][cin][cout] -> bf16 [t][cout][cin]; pad tap T zeroed
__global__ __launch_bounds__(256) void prep_w_all(PrepArgs a) {
    const int l = blockIdx.y;
    const int i = blockIdx.x * 256 + threadIdx.x;
    if (i >= a.total[l]) return;
    const int COUT = a.COUT[l], CIN = a.CIN[l], T = a.T[l];
    const int co = i % COUT; const int r = i / COUT; const int ci = r % CIN; const int t = r / CIN;
    unsigned short v = (t < T) ? f2bf(a.src[l][i]) : (unsigned short)0;
    a.dst[l][((size_t)t * COUT + co) * CIN + ci] = v;
}

// Layer 0: CIN=4 -> COUT=16
__global__ __launch_bounds__(256, 4) void sp_conv0(const float* __restrict__ fin,
                                                   const int* __restrict__ grid,
                                                   const int* __restrict__ oc, int n_out,
                                                   const float* __restrict__ w,
                                                   float* __restrict__ out,
                                                   int D, int H, int W) {
    const int c = threadIdx.x & 15;
    const int p = (blockIdx.x * 256 + threadIdx.x) >> 4;
    if (p >= n_out) return;
    const int b   = oc[4*p+0];
    const int iz0 = oc[4*p+1] - 1;
    const int iy0 = oc[4*p+2] - 1;
    const int ix0 = oc[4*p+3] - 1;
    const int* gb = grid + b * (D * H * W);
    float acc = 0.f;
    for (int kd = 0; kd < 3; ++kd) {
        const int iz = iz0 + kd;
        if ((unsigned)iz >= (unsigned)D) continue;
        for (int kh = 0; kh < 3; ++kh) {
            const int iy = iy0 + kh;
            if ((unsigned)iy >= (unsigned)H) continue;
            for (int kw = 0; kw < 3; ++kw) {
                const int ix = ix0 + kw;
                if ((unsigned)ix >= (unsigned)W) continue;
                const int idx = gb[(iz*H + iy)*W + ix];
                if (idx < 0) continue;
                const float4 v = *(const float4*)(fin + (size_t)idx * 4);
                const float* wp = w + (size_t)((kd*3 + kh)*3 + kw) * 64 + c;
                acc = fmaf(v.x, wp[0],  acc);
                acc = fmaf(v.y, wp[16], acc);
                acc = fmaf(v.z, wp[32], acc);
                acc = fmaf(v.w, wp[48], acc);
            }
        }
    }
    out[(size_t)p*16 + c] = acc;
}

// ---------------------------------------------------------------------------
// LDS path, CIN=16 (layers 1,2). (MB=4, BT=4.)
// ---------------------------------------------------------------------------
template<int COUT>
__global__ __launch_bounds__(256, 4) void sp_conv_lds16(
    const unsigned short* __restrict__ fin, const int* __restrict__ grid,
    const int* __restrict__ oc, int n_out,
    const unsigned short* __restrict__ wt, float* __restrict__ out,
    float* __restrict__ stats,
    int D, int H, int W, int sz, int sy, int sx, int pz, int py, int px)
{
    constexpr int T  = 27;
    constexpr int BT = 4;
    constexpr int TP = 28;
    constexpr int NT = COUT/16;
    constexpr int NB = (COUT == 16) ? BT/2 : BT;

    __shared__ unsigned short Abuf[4*BT*16*16];
    __shared__ unsigned short Bbuf[BT*COUT*16];
    __shared__ float ls[2*COUT];

    const int l     = threadIdx.x & 63;
    const int w     = threadIdx.x >> 6;
    const int n     = l & 15;
    const int quad  = l >> 4;
    const int pbase = xcd_swz(blockIdx.x, gridDim.x) * 64 + w * 16;

    if (threadIdx.x < 2*COUT) ls[threadIdx.x] = 0.f;

    int idx[TP];
    if (quad == 0) {
        int pc = pbase + n;
        if (pc > n_out - 1) pc = n_out - 1;
        const int4 cc = ((const int4*)oc)[pc];
        const int* gb = grid + cc.x * (D * H * W);
        const int iz0 = cc.y * sz - pz;
        const int iy0 = cc.z * sy - py;
        const int ix0 = cc.w * sx - px;
#pragma unroll
        for (int tap = 0; tap < TP; ++tap) {
            const int te = tap < T ? tap : 0;
            const int kd = te/9, kr = te%9, kh = kr/3, kw = kr%3;
            const int iz = iz0 + kd, iy = iy0 + kh, ix = ix0 + kw;
            const bool ok = (tap < T) && (unsigned)iz < (unsigned)D &&
                            (unsigned)iy < (unsigned)H && (unsigned)ix < (unsigned)W;
            const int cz = iz < 0 ? 0 : (iz >= D ? D-1 : iz);
            const int cy = iy < 0 ? 0 : (iy >= H ? H-1 : iy);
            const int cx = ix < 0 ? 0 : (ix >= W ? W-1 : ix);
            const int g = gb[(cz*H + cy)*W + cx];
            idx[tap] = ok ? g : -1;
        }
    }

    f32x4 acc[NT];
#pragma unroll
    for (int t = 0; t < NT; ++t) acc[t] = (f32x4){0.f, 0.f, 0.f, 0.f};

    const int h  = l >> 5;
    const int m  = (l >> 1) & 15;
    const int ch = l & 1;

#pragma unroll
    for (int tb0 = 0; tb0 < TP; tb0 += BT) {
#pragma unroll
        for (int q = 0; q < BT/2; ++q) {
            const int v0 = __shfl(idx[tb0 + 2*q],     m);
            const int v1 = __shfl(idx[tb0 + 2*q + 1], m);
            const int row = h ? v1 : v0;
            const unsigned short* gp = fin + (ptrdiff_t)row*16 + ch*8;
            unsigned short* lp = Abuf + (w*BT + 2*q)*16*16;
            dma16(gp, lp);
        }
        for (int q = w; q < NB; q += 4) {
            if constexpr (COUT == 16) {
                const int tap = tb0 + 2*q + h;
                const int tw = tap < T ? tap : T;
                const unsigned short* gp = wt + ((size_t)tw*COUT + m)*16 + ch*8;
                unsigned short* lp = Bbuf + (2*q)*COUT*16;
                dma16(gp, lp);
            } else {
                const int tap = tb0 + q;
                const int tw = tap < T ? tap : T;
                const int r = l >> 1;
                const unsigned short* gp = wt + ((size_t)tw*COUT + r)*16 + ch*8;
                unsigned short* lp = Bbuf + q*COUT*16;
                dma16(gp, lp);
            }
        }
        __syncthreads();
#pragma unroll
        for (int jp = 0; jp < BT/2; ++jp) {
            const int ts = 2*jp + (quad >> 1);
            bf16x8 a = *(const bf16x8*)(Abuf + ((w*BT + ts)*16 + n)*16 + (quad & 1)*8);
#pragma unroll
            for (int t = 0; t < NT; ++t) {
                bf16x8 b = *(const bf16x8*)(Bbuf + (ts*COUT + t*16 + n)*16 + (quad & 1)*8);
                acc[t] = __builtin_amdgcn_mfma_f32_16x16x32_bf16(a, b, acc[t], 0, 0, 0);
            }
        }
        __syncthreads();
    }

#pragma unroll
    for (int t = 0; t < NT; ++t)
#pragma unroll
        for (int r = 0; r < 4; ++r) {
            const int p = pbase + quad*4 + r;
            if (p < n_out) out[(size_t)p * COUT + t*16 + n] = acc[t][r];
        }

#pragma unroll
    for (int t = 0; t < NT; ++t) {
        float s1 = 0.f, s2 = 0.f;
#pragma unroll
        for (int r = 0; r < 4; ++r) {
            const int p = pbase + quad*4 + r;
            if (p < n_out) { const float v = acc[t][r]; s1 += v; s2 += v*v; }
        }
        s1 += __shfl_xor(s1, 16); s2 += __shfl_xor(s2, 16);
        s1 += __shfl_xor(s1, 32); s2 += __shfl_xor(s2, 32);
        if (quad == 0) {
            atomicAdd(&ls[t*16 + n], s1);
            atomicAdd(&ls[COUT + t*16 + n], s2);
        }
    }
    __syncthreads();
    if (threadIdx.x < 2*COUT) atomicAdd(&stats[threadIdx.x], ls[threadIdx.x]);
}

// ---------------------------------------------------------------------------
// 64-pt LDS path, CIN>=32: small-N layers (L8-L11). Latency-optimal BT.
// ---------------------------------------------------------------------------
template<int CIN, int COUT, int BT, int KD, int KH, int KW, int MB>
__global__ __launch_bounds__(256, MB) void sp_conv_lds(
    const unsigned short* __restrict__ fin, const int* __restrict__ grid,
    const int* __restrict__ oc, int n_out,
    const unsigned short* __restrict__ wt, float* __restrict__ out,
    float* __restrict__ stats,
    int D, int H, int W, int sz, int sy, int sx, int pz, int py, int px)
{
    constexpr int T    = KD*KH*KW;
    constexpr int TP   = ((T + BT - 1)/BT)*BT;
    constexpr int NT   = COUT/16;
    constexpr int S    = CIN/32;
    constexpr int LPR  = CIN/8;
    constexpr int RPD  = 64/LPR;
    constexpr int ADMA = 16/RPD;
    constexpr int BDMA = COUT/RPD;

    __shared__ unsigned short Abuf[4*BT*16*CIN];
    __shared__ unsigned short Bbuf[BT*COUT*CIN];
    __shared__ float ls[2*COUT];

    const int l     = threadIdx.x & 63;
    const int w     = threadIdx.x >> 6;
    const int n     = l & 15;
    const int quad  = l >> 4;
    const int pbase = xcd_swz(blockIdx.x, gridDim.x) * 64 + w * 16;

    if (threadIdx.x < 2*COUT) ls[threadIdx.x] = 0.f;

    int idx[TP];
    if (quad == 0) {
        int pc = pbase + n;
        if (pc > n_out - 1) pc = n_out - 1;
        const int4 cc = ((const int4*)oc)[pc];
        const int* gb = grid + cc.x * (D * H * W);
        const int iz0 = cc.y * sz - pz;
        const int iy0 = cc.z * sy - py;
        const int ix0 = cc.w * sx - px;
#pragma unroll
        for (int tap = 0; tap < TP; ++tap) {
            const int te = tap < T ? tap : 0;
            const int kd = te/(KH*KW), kr = te%(KH*KW), kh = kr/KW, kw = kr%KW;
            const int iz = iz0 + kd, iy = iy0 + kh, ix = ix0 + kw;
            const bool ok = (tap < T) && (unsigned)iz < (unsigned)D &&
                            (unsigned)iy < (unsigned)H && (unsigned)ix < (unsigned)W;
            const int cz = iz < 0 ? 0 : (iz >= D ? D-1 : iz);
            const int cy = iy < 0 ? 0 : (iy >= H ? H-1 : iy);
            const int cx = ix < 0 ? 0 : (ix >= W ? W-1 : ix);
            const int g = gb[(cz*H + cy)*W + cx];
            idx[tap] = ok ? g : -1;
        }
    }

    f32x4 acc[NT];
#pragma unroll
    for (int t = 0; t < NT; ++t) acc[t] = (f32x4){0.f, 0.f, 0.f, 0.f};

#pragma unroll
    for (int tb0 = 0; tb0 < TP; tb0 += BT) {
#pragma unroll
        for (int j = 0; j < BT; ++j) {
#pragma unroll
            for (int d = 0; d < ADMA; ++d) {
                const int m  = d*RPD + l/LPR;
                const int i0 = __shfl(idx[tb0+j], m);
                const int slot = (l % LPR) ^ (m % LPR);
                const unsigned short* gp = fin + (ptrdiff_t)i0*CIN + slot*8;
                unsigned short* lp = Abuf + ((w*BT + j)*16 + d*RPD)*CIN;
                dma16(gp, lp);
            }
        }
        for (int q = w; q < BT*BDMA; q += 4) {
            const int j = q / BDMA, d = q % BDMA;
            const int t = tb0 + j;
            const int tw = t < T ? t : T;
            const int r  = d*RPD + l/LPR;
            const int slot = (l % LPR) ^ (r % LPR);
            const unsigned short* gp = wt + ((size_t)tw*COUT + r)*CIN + slot*8;
            unsigned short* lp = Bbuf + (j*COUT + d*RPD)*CIN;
            dma16(gp, lp);
        }
        __syncthreads();
#pragma unroll
        for (int j = 0; j < BT; ++j) {
            const unsigned short* Aw = Abuf + (w*BT + j)*16*CIN;
            const unsigned short* Bw = Bbuf + j*COUT*CIN;
#pragma unroll
            for (int s = 0; s < S; ++s) {
                const int c = s*4 + quad;
                bf16x8 a = *(const bf16x8*)(Aw + n*CIN + ((c ^ (n % LPR)) * 8));
#pragma unroll
                for (int t = 0; t < NT; ++t) {
                    const int r = t*16 + n;
                    bf16x8 b = *(const bf16x8*)(Bw + r*CIN + ((c ^ (r % LPR)) * 8));
                    acc[t] = __builtin_amdgcn_mfma_f32_16x16x32_bf16(a, b, acc[t], 0, 0, 0);
                }
            }
        }
        __syncthreads();
    }

#pragma unroll
    for (int t = 0; t < NT; ++t)
#pragma unroll
        for (int r = 0; r < 4; ++r) {
            const int p = pbase + quad*4 + r;
            if (p < n_out) out[(size_t)p * COUT + t*16 + n] = acc[t][r];
        }

#pragma unroll
    for (int t = 0; t < NT; ++t) {
        float s1 = 0.f, s2 = 0.f;
#pragma unroll
        for (int r = 0; r < 4; ++r) {
            const int p = pbase + quad*4 + r;
            if (p < n_out) { const float v = acc[t][r]; s1 += v; s2 += v*v; }
        }
        s1 += __shfl_xor(s1, 16); s2 += __shfl_xor(s2, 16);
        s1 += __shfl_xor(s1, 32); s2 += __shfl_xor(s2, 32);
        if (quad == 0) {
            atomicAdd(&ls[t*16 + n], s1);
            atomicAdd(&ls[COUT + t*16 + n], s2);
        }
    }
    __syncthreads();
    if (threadIdx.x < 2*COUT) atomicAdd(&stats[threadIdx.x], ls[threadIdx.x]);
}

// ---------------------------------------------------------------------------
// Multi-m-tile LDS path, CIN>=32, T=27: big layers (L3,L4,L5). Wave owns
// MT*16 points -> B-staging amortized over MT x outputs.
// ---------------------------------------------------------------------------
template<int CIN, int COUT, int BT, int MT, int MB>
__global__ __launch_bounds__(256, MB) void sp_conv_big(
    const unsigned short* __restrict__ fin, const int* __restrict__ grid,
    const int* __restrict__ oc, int n_out,
    const unsigned short* __restrict__ wt, float* __restrict__ out,
    float* __restrict__ stats,
    int D, int H, int W, int sz, int sy, int sx, int pz, int py, int px)
{
    constexpr int T    = 27;
    constexpr int TP   = ((T + BT - 1)/BT)*BT;
    constexpr int PPW  = MT*16;
    constexpr int NT   = COUT/16;
    constexpr int S    = CIN/32;
    constexpr int LPR  = CIN/8;
    constexpr int RPD  = 64/LPR;
    constexpr int ADMA = PPW/RPD;
    constexpr int BDMA = COUT/RPD;

    __shared__ unsigned short Abuf[4*BT*PPW*CIN];
    __shared__ unsigned short Bbuf[BT*COUT*CIN];
    __shared__ float ls[2*COUT];

    const int l     = threadIdx.x & 63;
    const int w     = threadIdx.x >> 6;
    const int n     = l & 15;
    const int quad  = l >> 4;
    const int wbase = xcd_swz(blockIdx.x, gridDim.x) * (4*PPW) + w * PPW;

    if (threadIdx.x < 2*COUT) ls[threadIdx.x] = 0.f;

    int idx[TP];
    {
        int pc = wbase + (l % PPW);
        if (pc > n_out - 1) pc = n_out - 1;
        const int4 cc = ((const int4*)oc)[pc];
        const int* gb = grid + cc.x * (D * H * W);
        const int iz0 = cc.y * sz - pz;
        const int iy0 = cc.z * sy - py;
        const int ix0 = cc.w * sx - px;
#pragma unroll
        for (int tap = 0; tap < TP; ++tap) {
            const int te = tap < T ? tap : 0;
            const int kd = te/9, kr = te%9, kh = kr/3, kw = kr%3;
            const int iz = iz0 + kd, iy = iy0 + kh, ix = ix0 + kw;
            const bool ok = (tap < T) && (unsigned)iz < (unsigned)D &&
                            (unsigned)iy < (unsigned)H && (unsigned)ix < (unsigned)W;
            const int cz = iz < 0 ? 0 : (iz >= D ? D-1 : iz);
            const int cy = iy < 0 ? 0 : (iy >= H ? H-1 : iy);
            const int cx = ix < 0 ? 0 : (ix >= W ? W-1 : ix);
            const int g = gb[(cz*H + cy)*W + cx];
            idx[tap] = ok ? g : -1;
        }
    }

    f32x4 acc[MT][NT];
#pragma unroll
    for (int mt = 0; mt < MT; ++mt)
#pragma unroll
        for (int t = 0; t < NT; ++t) acc[mt][t] = (f32x4){0.f, 0.f, 0.f, 0.f};

#pragma unroll
    for (int tb0 = 0; tb0 < TP; tb0 += BT) {
#pragma unroll
        for (int j = 0; j < BT; ++j) {
#pragma unroll
            for (int d = 0; d < ADMA; ++d) {
                const int r  = d*RPD + l/LPR;
                const int i0 = __shfl(idx[tb0+j], r);
                const int slot = (l % LPR) ^ (r % LPR);
                const unsigned short* gp = fin + (ptrdiff_t)i0*CIN + slot*8;
                unsigned short* lp = Abuf + ((w*BT + j)*PPW + d*RPD)*CIN;
                dma16(gp, lp);
            }
        }
        for (int q = w; q < BT*BDMA; q += 4) {
            const int j = q / BDMA, d = q % BDMA;
            const int t = tb0 + j;
            const int tw = t < T ? t : T;
            const int r  = d*RPD + l/LPR;
            const int slot = (l % LPR) ^ (r % LPR);
            const unsigned short* gp = wt + ((size_t)tw*COUT + r)*CIN + slot*8;
            unsigned short* lp = Bbuf + (j*COUT + d*RPD)*CIN;
            dma16(gp, lp);
        }
        __syncthreads();
#pragma unroll
        for (int j = 0; j < BT; ++j) {
            const unsigned short* Aw = Abuf + (w*BT + j)*PPW*CIN;
            const unsigned short* Bw = Bbuf + j*COUT*CIN;
#pragma unroll
            for (int s = 0; s < S; ++s) {
                const int c = s*4 + quad;
                bf16x8 bfr[NT];
#pragma unroll
                for (int t = 0; t < NT; ++t) {
                    const int r = t*16 + n;
                    bfr[t] = *(const bf16x8*)(Bw + r*CIN + ((c ^ (r % LPR)) * 8));
                }
#pragma unroll
                for (int mt = 0; mt < MT; ++mt) {
                    bf16x8 a = *(const bf16x8*)(Aw + (mt*16 + n)*CIN + ((c ^ (n % LPR)) * 8));
#pragma unroll
                    for (int t = 0; t < NT; ++t)
                        acc[mt][t] = __builtin_amdgcn_mfma_f32_16x16x32_bf16(a, bfr[t], acc[mt][t], 0, 0, 0);
                }
            }
        }
        __syncthreads();
    }

#pragma unroll
    for (int mt = 0; mt < MT; ++mt)
#pragma unroll
        for (int t = 0; t < NT; ++t)
#pragma unroll
            for (int r = 0; r < 4; ++r) {
                const int p = wbase + mt*16 + quad*4 + r;
                if (p < n_out) out[(size_t)p * COUT + t*16 + n] = acc[mt][t][r];
            }

#pragma unroll
    for (int t = 0; t < NT; ++t) {
        float s1 = 0.f, s2 = 0.f;
#pragma unroll
        for (int mt = 0; mt < MT; ++mt)
#pragma unroll
            for (int r = 0; r < 4; ++r) {
                const int p = wbase + mt*16 + quad*4 + r;
                if (p < n_out) { const float v = acc[mt][t][r]; s1 += v; s2 += v*v; }
            }
        s1 += __shfl_xor(s1, 16); s2 += __shfl_xor(s2, 16);
        s1 += __shfl_xor(s1, 32); s2 += __shfl_xor(s2, 32);
        if (quad == 0) {
            atomicAdd(&ls[t*16 + n], s1);
            atomicAdd(&ls[COUT + t*16 + n], s2);
        }
    }
    __syncthreads();
    if (threadIdx.x < 2*COUT) atomicAdd(&stats[threadIdx.x], ls[threadIdx.x]);
}

// ---------------------------------------------------------------------------
// Dense tiled conv (stride 1, 3x3x3, pad 1, CIN==COUT==C=64): layers 6,7.
// ---------------------------------------------------------------------------
template<int C, int TZ, int TY, int TX, int BTW, int MB>
__global__ __launch_bounds__(256, MB) void sp_conv_dense(
    const unsigned short* __restrict__ dense, const int* __restrict__ grid,
    const unsigned short* __restrict__ wt, float* __restrict__ out,
    float* __restrict__ stats, const unsigned short* __restrict__ zrow,
    int D, int H, int W, int ZTn, int YTn, int XTn)
{
    constexpr int T   = 27;
    constexpr int HZ = TZ+2, HY = TY+2, HX = TX+2;
    constexpr int R   = HZ*HY*HX;
    constexpr int LPR = C/8;
    constexpr int RPD = 64/LPR;
    constexpr int RPI = 4*RPD;
    constexpr int NDMA = (R + RPI - 1)/RPI;
    constexpr int RPAD = NDMA*RPI;
    constexpr int M   = TZ*TY*TX;
    constexpr int WPW = M/4;
    constexpr int MT  = WPW/16;
    constexpr int NT  = C/16;
    constexpr int S   = C/32;
    constexpr int BDMA = C/RPD;

    __shared__ unsigned short Hbuf[RPAD*C];
    __shared__ unsigned short Bbuf[BTW*C*C];
    __shared__ float ls[2*C];

    const int l    = threadIdx.x & 63;
    const int w    = threadIdx.x >> 6;
    const int n    = l & 15;
    const int quad = l >> 4;

    int r1 = blockIdx.x;
    const int xt = r1 % XTn; r1 /= XTn;
    const int yt = r1 % YTn; r1 /= YTn;
    const int zt = r1 % ZTn; r1 /= ZTn;
    const int b  = r1;
    const int z0 = zt*TZ, y0 = yt*TY, x0 = xt*TX;
    const int* gb = grid + b * (D*H*W);
    const size_t dbase = (size_t)b * D*H*W;

    if (threadIdx.x < 2*C) ls[threadIdx.x] = 0.f;

#pragma unroll
    for (int d = 0; d < NDMA; ++d) {
        const int r0  = (d*4 + w)*RPD;
        const int row = r0 + l/LPR;
        const int slot = (l % LPR) ^ (row % LPR);
        const unsigned short* gp;
        if (row < R) {
            const int hz = row/(HY*HX);
            const int hy = (row/HX) % HY;
            const int hx = row % HX;
            const int gz = z0 - 1 + hz, gy = y0 - 1 + hy, gx = x0 - 1 + hx;
            const bool ok = (unsigned)gz < (unsigned)D && (unsigned)gy < (unsigned)H &&
                            (unsigned)gx < (unsigned)W;
            gp = ok ? dense + (dbase + (size_t)(gz*H + gy)*W + gx)*C + slot*8
                    : zrow + (l % LPR)*8;
        } else {
            gp = zrow + (l % LPR)*8;
        }
        dma16(gp, Hbuf + r0*C);
    }

    int prow[MT];
#pragma unroll
    for (int mt = 0; mt < MT; ++mt) {
        const int pos = w*WPW + mt*16 + n;
        const int dz = pos/(TY*TX), dy = (pos/TX)%TY, dx = pos%TX;
        prow[mt] = dz*(HY*HX) + dy*HX + dx;
    }

    f32x4 acc[MT][NT];
#pragma unroll
    for (int mt = 0; mt < MT; ++mt)
#pragma unroll
        for (int t = 0; t < NT; ++t) acc[mt][t] = (f32x4){0.f, 0.f, 0.f, 0.f};

#pragma unroll
    for (int batch = 0; batch < (T + BTW - 1)/BTW; ++batch) {
        const int tb0 = batch*BTW;
        const int nb  = (tb0 + BTW <= T) ? BTW : T - tb0;
        for (int q = w; q < nb*BDMA; q += 4) {
            const int j = q / BDMA, d = q % BDMA;
            const int tap = tb0 + j;
            const int rr  = d*RPD + l/LPR;
            const int slot = (l % LPR) ^ (rr % LPR);
            dma16(wt + ((size_t)tap*C + rr)*C + slot*8, Bbuf + (j*C + d*RPD)*C);
        }
        __syncthreads();
#pragma unroll
        for (int j = 0; j < nb; ++j) {
            const int tap = tb0 + j;
            const int kd = tap/9, kh = (tap/3)%3, kw = tap%3;
            const int toff = kd*(HY*HX) + kh*HX + kw;
#pragma unroll
            for (int s = 0; s < S; ++s) {
                const int c = s*4 + quad;
                bf16x8 bfr[NT];
#pragma unroll
                for (int t = 0; t < NT; ++t) {
                    const int rr = t*16 + n;
                    bfr[t] = *(const bf16x8*)(Bbuf + (j*C + rr)*C + ((c ^ (rr & (LPR-1)))*8));
                }
#pragma unroll
                for (int mt = 0; mt < MT; ++mt) {
                    const int arow = prow[mt] + toff;
                    bf16x8 a = *(const bf16x8*)(Hbuf + arow*C + ((c ^ (arow & (LPR-1)))*8));
#pragma unroll
                    for (int t = 0; t < NT; ++t)
                        acc[mt][t] = __builtin_amdgcn_mfma_f32_16x16x32_bf16(a, bfr[t], acc[mt][t], 0, 0, 0);
                }
            }
        }
        __syncthreads();
    }

    float s1[NT], s2[NT];
#pragma unroll
    for (int t = 0; t < NT; ++t) { s1[t] = 0.f; s2[t] = 0.f; }
#pragma unroll
    for (int mt = 0; mt < MT; ++mt) {
#pragma unroll
        for (int r = 0; r < 4; ++r) {
            const int pos = w*WPW + mt*16 + quad*4 + r;
            const int dz = pos/(TY*TX), dy = (pos/TX)%TY, dx = pos%TX;
            const int gz = z0 + dz, gy = y0 + dy, gx = x0 + dx;
            int p = -1;
            if (gz < D && gy < H && gx < W) p = gb[(gz*H + gy)*W + gx];
            if (p >= 0) {
#pragma unroll
                for (int t = 0; t < NT; ++t) {
                    const float v = acc[mt][t][r];
                    out[(size_t)p*C + t*16 + n] = v;
                    s1[t] += v; s2[t] += v*v;
                }
            }
        }
    }
#pragma unroll
    for (int t = 0; t < NT; ++t) {
        float a1 = s1[t], a2 = s2[t];
        a1 += __shfl_xor(a1, 16); a2 += __shfl_xor(a2, 16);
        a1 += __shfl_xor(a1, 32); a2 += __shfl_xor(a2, 32);
        if (quad == 0) {
            atomicAdd(&ls[t*16 + n], a1);
            atomicAdd(&ls[C + t*16 + n], a2);
        }
    }
    __syncthreads();
    if (threadIdx.x < 2*C) atomicAdd(&stats[threadIdx.x], ls[threadIdx.x]);
}

template<int C>
__global__ __launch_bounds__(256) void reduce_stats(const float* __restrict__ x, int nn,
                                                    float* __restrict__ stats)
{
    constexpr int R = 256 / C;
    __shared__ float s1[256];
    __shared__ float s2[256];
    const int c = threadIdx.x % C;
    const int r = threadIdx.x / C;
    float a1 = 0.f, a2 = 0.f;
    for (int i = blockIdx.x * R + r; i < nn; i += R * gridDim.x) {
        float v = x[(size_t)i*C + c];
        a1 += v;
        a2 += v * v;
    }
    s1[threadIdx.x] = a1;
    s2[threadIdx.x] = a2;
    __syncthreads();
    for (int off = 128; off >= C; off >>= 1) {
        if (threadIdx.x < off) {
            s1[threadIdx.x] += s1[threadIdx.x + off];
            s2[threadIdx.x] += s2[threadIdx.x + off];
        }
        __syncthreads();
    }
    if (threadIdx.x < C) {
        atomicAdd(&stats[c],     s1[threadIdx.x]);
        atomicAdd(&stats[C + c], s2[threadIdx.x]);
    }
}

__device__ inline void stv4(float* p, float4 v) { *(float4*)p = v; }
__device__ inline void stv4(unsigned short* p, float4 v) {
    bf16x4s o;
    o.x = (short)f2bf(v.x); o.y = (short)f2bf(v.y);
    o.z = (short)f2bf(v.z); o.w = (short)f2bf(v.w);
    *(bf16x4s*)p = o;
}

__device__ inline float4 bn_math(float4 xv, float4 s1, float4 s2, float4 gm, float4 bt,
                                 float inv_n) {
    float4 o;
    { float mu=s1.x*inv_n, var=s2.x*inv_n-mu*mu, g=gm.x*rsqrtf(var+1e-3f);
      float v=(xv.x-mu)*g+bt.x; o.x = v>0.f? v:0.f; }
    { float mu=s1.y*inv_n, var=s2.y*inv_n-mu*mu, g=gm.y*rsqrtf(var+1e-3f);
      float v=(xv.y-mu)*g+bt.y; o.y = v>0.f? v:0.f; }
    { float mu=s1.z*inv_n, var=s2.z*inv_n-mu*mu, g=gm.z*rsqrtf(var+1e-3f);
      float v=(xv.z-mu)*g+bt.z; o.z = v>0.f? v:0.f; }
    { float mu=s1.w*inv_n, var=s2.w*inv_n-mu*mu, g=gm.w*rsqrtf(var+1e-3f);
      float v=(xv.w-mu)*g+bt.w; o.w = v>0.f? v:0.f; }
    return o;
}

template<int C, typename OUT>
__global__ __launch_bounds__(256) void bn_relu_apply(const float* __restrict__ x,
                                                     OUT* __restrict__ y, int nn,
                                                     const float* __restrict__ stats,
                                                     const float* __restrict__ gamma,
                                                     const float* __restrict__ beta)
{
    const size_t q = (size_t)blockIdx.x * blockDim.x + threadIdx.x;
    if (q >= (size_t)nn * (C/4)) return;
    const int c = (int)(q % (size_t)(C/4)) * 4;
    const float4 o = bn_math(*(const float4*)(x + q*4),
                             *(const float4*)(stats + c), *(const float4*)(stats + C + c),
                             *(const float4*)(gamma + c), *(const float4*)(beta + c),
                             1.f / (float)nn);
    stv4(y + q*4, o);
}

// bn+relu writing into the dense [b,z,y,x,C] bf16 buffer (for dense conv input)
template<int C>
__global__ __launch_bounds__(256) void bn_relu_apply_dense(const float* __restrict__ x,
                                                           unsigned short* __restrict__ dense,
                                                           int nn,
                                                           const float* __restrict__ stats,
                                                           const float* __restrict__ gamma,
                                                           const float* __restrict__ beta,
                                                           const int* __restrict__ coords,
                                                           int D, int H, int W)
{
    const size_t q = (size_t)blockIdx.x * blockDim.x + threadIdx.x;
    if (q >= (size_t)nn * (C/4)) return;
    const int c = (int)(q % (size_t)(C/4)) * 4;
    const int p = (int)(q / (size_t)(C/4));
    const float4 o = bn_math(*(const float4*)(x + q*4),
                             *(const float4*)(stats + c), *(const float4*)(stats + C + c),
                             *(const float4*)(gamma + c), *(const float4*)(beta + c),
                             1.f / (float)nn);
    const int4 cc = ((const int4*)coords)[p];
    const size_t cell = ((size_t)((cc.x*D + cc.y)*H + cc.z)*W + cc.w);
    stv4(dense + cell*C + c, o);
}

extern "C" void kernel_launch(void* const* d_in, const int* in_sizes, int n_in,
                              void* d_out, int out_size, void* d_ws, size_t ws_size,
                              hipStream_t stream) {
    const float* WPTR[12] = {
        (const float*)d_in[1], (const float*)d_in[2], (const float*)d_in[3],
        (const float*)d_in[4], (const float*)d_in[5], (const float*)d_in[6],
        (const float*)d_in[7], (const float*)d_in[8], (const float*)d_in[9],
        (const float*)d_in[10], (const float*)d_in[11], (const float*)d_in[12] };
    const float* vf    = (const float*)d_in[0];
    const float* gamma = (const float*)d_in[13];
    const float* beta  = (const float*)d_in[14];
    const int* c1 = (const int*)d_in[15];
    const int* c2 = (const int*)d_in[16];
    const int* c3 = (const int*)d_in[17];
    const int* c4 = (const int*)d_in[18];
    const int* c5 = (const int*)d_in[19];
    const int N1 = in_sizes[15] / 4;
    const int N2 = in_sizes[16] / 4;
    const int N3 = in_sizes[17] / 4;
    const int N4 = in_sizes[18] / 4;
    const int N5 = in_sizes[19] / 4;

    static const int LT[12]  = {27,27,27,27,27,27,27,27,27,27,27,3};
    static const int LCI[12] = {4,16,16,32,32,32,64,64,64,64,64,64};
    static const int LCO[12] = {16,16,32,32,32,64,64,64,64,64,64,128};

    const size_t G1 = (size_t)2*41*160*160;
    const size_t G2 = (size_t)2*21*80*80;
    const size_t G3 = (size_t)2*11*40*40;
    const size_t G4 = (size_t)2*5*20*20;
    int* grid1 = (int*)d_ws;
    int* grid2 = grid1 + G1;
    int* grid3 = grid2 + G2;
    int* grid4 = grid3 + G3;
    float* stats = (float*)(grid4 + G4);

    size_t maxE = (size_t)N1*16;
    if ((size_t)N2*32  > maxE) maxE = (size_t)N2*32;
    if ((size_t)N3*64  > maxE) maxE = (size_t)N3*64;
    if ((size_t)N4*64  > maxE) maxE = (size_t)N4*64;
    if ((size_t)N5*128 > maxE) maxE = (size_t)N5*128;
    maxE = (maxE + 7) & ~(size_t)7;

    float* raw = stats + 12*256;
    unsigned short* padA = (unsigned short*)(raw + maxE);
    unsigned short* fA   = padA + 128;              // zero row at fA - CIN
    unsigned short* padB = fA + maxE;
    unsigned short* fB   = padB + 128;
    unsigned short* wtb  = fB + maxE;
    size_t wtoff[12];
    size_t wtot = 0;
    {
        size_t o = 0;
        for (int i = 1; i < 12; ++i) {
            wtoff[i] = o;
            o += (size_t)(LT[i] + 1) * LCI[i] * LCO[i];
        }
        wtot = (o + 15) & ~(size_t)15;
    }
    unsigned short* dbuf = wtb + wtot;              // dense buffer: 2*11*40*40*64 shorts

    hipMemsetAsync(grid1, 0xFF, (G1+G2+G3+G4)*sizeof(int), stream);
    hipMemsetAsync(stats, 0, 12*256*sizeof(float), stream);
    hipMemsetAsync(padA, 0, 128*sizeof(unsigned short), stream);
    hipMemsetAsync(padB, 0, 128*sizeof(unsigned short), stream);

    {
        ScatterArgs sa;
        sa.coords[0]=c1; sa.coords[1]=c2; sa.coords[2]=c3; sa.coords[3]=c4;
        sa.grid[0]=grid1; sa.grid[1]=grid2; sa.grid[2]=grid3; sa.grid[3]=grid4;
        sa.n[0]=N1; sa.n[1]=N2; sa.n[2]=N3; sa.n[3]=N4;
        sa.D[0]=41; sa.H[0]=160; sa.W[0]=160;
        sa.D[1]=21; sa.H[1]= 80; sa.W[1]= 80;
        sa.D[2]=11; sa.H[2]= 40; sa.W[2]= 40;
        sa.D[3]= 5; sa.H[3]= 20; sa.W[3]= 20;
        int mx = N1; if (N2>mx) mx=N2; if (N3>mx) mx=N3; if (N4>mx) mx=N4;
        dim3 g((mx + 255)/256, 4);
        scatter_grid_all<<<g, 256, 0, stream>>>(sa);
    }
    {
        PrepArgs pa;
        int mx = 0;
        for (int i = 1; i < 12; ++i) {
            pa.src[i-1] = WPTR[i];
            pa.dst[i-1] = wtb + wtoff[i];
            pa.T[i-1] = LT[i]; pa.CIN[i-1] = LCI[i]; pa.COUT[i-1] = LCO[i];
            pa.total[i-1] = (LT[i]+1)*LCI[i]*LCO[i];
            if (pa.total[i-1] > mx) mx = pa.total[i-1];
        }
        dim3 g((mx + 255)/256, 11);
        prep_w_all<<<g, 256, 0, stream>>>(pa);
    }

    enum { GOFF_0 = 0, GOFF_1 = 16, GOFF_2 = 32, GOFF_3 = 64, GOFF_4 = 96, GOFF_5 = 128,
           GOFF_6 = 192, GOFF_7 = 256, GOFF_8 = 320, GOFF_9 = 384, GOFF_10 = 448, GOFF_11 = 512 };

#define APPLY(i, COUT, NP, FOUT_T, FOUT) \
    bn_relu_apply<COUT, FOUT_T><<<(((size_t)(NP)*(COUT)/4) + 255)/256, 256, 0, stream>>>( \
        raw, FOUT, NP, stats + (i)*256, gamma + GOFF_##i, beta + GOFF_##i);

#define APPLYD(i, C, NP, CC, D,H,W) \
    hipMemsetAsync(dbuf, 0, (size_t)2*(D)*(H)*(W)*(C)*2, stream); \
    bn_relu_apply_dense<C><<<(((size_t)(NP)*(C)/4) + 255)/256, 256, 0, stream>>>( \
        raw, dbuf, NP, stats + (i)*256, gamma + GOFF_##i, beta + GOFF_##i, CC, D,H,W);

    sp_conv0<<<((size_t)N1*16 + 255)/256, 256, 0, stream>>>(vf, grid1, c1, N1, WPTR[0], raw, 41,160,160);
    { int rb = (N1 + 15)/16; if (rb > 240) rb = 240;
      reduce_stats<16><<<rb, 256, 0, stream>>>(raw, N1, stats + 0*256); }
    APPLY(0, 16, N1, unsigned short, fA);

#define CONVS(i, COUT, FIN, GRD, OC, NP, D,H,W, SZ,SY,SX, PZ,PY,PX) \
    sp_conv_lds16<COUT><<<((NP)+63)/64, 256, 0, stream>>>( \
        FIN, GRD, OC, NP, wtb + wtoff[i], raw, stats + (i)*256, D,H,W, SZ,SY,SX, PZ,PY,PX);

#define CONVL(i, CIN, COUT, BT, MB, KD,KH,KW, FIN, GRD, OC, NP, D,H,W, SZ,SY,SX, PZ,PY,PX) \
    sp_conv_lds<CIN,COUT,BT,KD,KH,KW,MB><<<((NP)+63)/64, 256, 0, stream>>>( \
        FIN, GRD, OC, NP, wtb + wtoff[i], raw, stats + (i)*256, D,H,W, SZ,SY,SX, PZ,PY,PX);

#define CONVB(i, CIN, COUT, BT, MT, MB, FIN, GRD, OC, NP, D,H,W, SZ,SY,SX, PZ,PY,PX) \
    sp_conv_big<CIN,COUT,BT,MT,MB><<<((NP)+(64*(MT))-1)/(64*(MT)), 256, 0, stream>>>( \
        FIN, GRD, OC, NP, wtb + wtoff[i], raw, stats + (i)*256, D,H,W, SZ,SY,SX, PZ,PY,PX);

#define CONVD(i, C, TZ,TY,TX, BTW, MB, GRD, D,H,W) \
    { const int zt = ((D)+(TZ)-1)/(TZ), yt = ((H)+(TY)-1)/(TY), xt = ((W)+(TX)-1)/(TX); \
      sp_conv_dense<C,TZ,TY,TX,BTW,MB><<<2*zt*yt*xt, 256, 0, stream>>>( \
          dbuf, GRD, wtb + wtoff[i], raw, stats + (i)*256, padA, D,H,W, zt,yt,xt); }

    CONVS( 1, 16,       fA, grid1, c1, N1, 41,160,160, 1,1,1, 1,1,1); APPLY( 1, 16, N1, unsigned short, fB);
    CONVS( 2, 32,       fB, grid1, c2, N2, 41,160,160, 2,2,2, 1,1,1); APPLY( 2, 32, N2, unsigned short, fA);
    CONVB ( 3, 32, 32, 3, 4, 2, fA, grid2, c2, N2, 21, 80, 80, 1,1,1, 1,1,1); APPLY( 3, 32, N2, unsigned short, fB);
    CONVB ( 4, 32, 32, 3, 4, 2, fB, grid2, c2, N2, 21, 80, 80, 1,1,1, 1,1,1); APPLY( 4, 32, N2, unsigned short, fA);
    CONVB ( 5, 32, 64, 3, 2, 3, fA, grid2, c3, N3, 21, 80, 80, 2,2,2, 1,1,1); APPLYD( 5, 64, N3, c3, 11,40,40);
    CONVD ( 6, 64, 4,4,8, 3, 2, grid3, 11,40,40);                          APPLYD( 6, 64, N3, c3, 11,40,40);
    CONVD ( 7, 64, 4,4,8, 3, 2, grid3, 11,40,40);                          APPLY( 7, 64, N3, unsigned short, fB);
    CONVL ( 8, 64, 64, 9, 1, 3,3,3, fB, grid3, c4, N4, 11, 40, 40, 2,2,2, 0,1,1); APPLY( 8, 64, N4, unsigned short, fA);
    CONVL ( 9, 64, 64, 9, 1, 3,3,3, fA, grid4, c4, N4,  5, 20, 20, 1,1,1, 1,1,1); APPLY( 9, 64, N4, unsigned short, fB);
    CONVL (10, 64, 64, 9, 1, 3,3,3, fB, grid4, c4, N4,  5, 20, 20, 1,1,1, 1,1,1); APPLY(10, 64, N4, unsigned short, fA);
    CONVL (11, 64,128, 3, 2, 3,1,1, fA, grid4, c5, N5,  5, 20, 20, 2,1,1, 0,0,0); APPLY(11, 128, N5, float, (float*)d_out);
#undef CONVS
#undef CONVL
#undef CONVB
#undef CONVD
#undef APPLY
#undef APPLYD
}